// Round 1
// baseline (188.623 us; speedup 1.0000x reference)
//
#include <hip/hip_runtime.h>

typedef unsigned short ushort_t;
typedef ushort_t ushort8 __attribute__((ext_vector_type(8)));
typedef __bf16 bf16x8 __attribute__((ext_vector_type(8)));
typedef float f32x4 __attribute__((ext_vector_type(4)));

#define B_      16
#define QL_     32
#define H_      32
#define HKV_    8
#define D_      128
#define MAXSEQ_ 8192
#define REP_    4
#define ROWS_   128
#define KT_     64
#define NT_     512
#define KS_LD   136   // 128 + 8 bf16 pad (16B) -> breaks stride-256B bank conflicts
#define VT_LD   72    // 64 + 8
#define PS_LD   72    // 64 + 8
#define NROWS_TOT (B_*HKV_*ROWS_)   // 16384

__device__ __forceinline__ ushort_t f2bf(float f) {
  unsigned u = __float_as_uint(f);
  return (ushort_t)((u + 0x7FFFu + ((u >> 16) & 1u)) >> 16);  // RNE, inputs finite
}

// Flash attention main kernel. Block = (b, kv_head, split). 8 waves, each owns
// 16 of the 128 (rep*QL) query rows. 16x16x32 bf16 MFMA; scores in log2 domain.
template<int NSPLIT, bool DIRECT>
__global__ __launch_bounds__(NT_, 2)
void fa_main(const float* __restrict__ qg, const float* __restrict__ kg,
             const float* __restrict__ vg, const float* __restrict__ kcg,
             const float* __restrict__ vcg, const int* __restrict__ cslp,
             float* __restrict__ outg, float* __restrict__ opart,
             float* __restrict__ mpart, float* __restrict__ lpart)
{
  __shared__ __align__(16) ushort_t Ks[KT_ * KS_LD];     // K tile, row-major [key][d]
  __shared__ __align__(16) ushort_t Vt[D_ * VT_LD];      // V tile transposed [d][key]
  __shared__ __align__(16) ushort_t Ps[8 * 16 * PS_LD];  // per-wave P [row][key]

  const int t    = threadIdx.x;
  const int s    = (int)blockIdx.x % NSPLIT;
  const int bh   = (int)blockIdx.x / NSPLIT;
  const int b    = bh / HKV_;
  const int h    = bh % HKV_;
  const int cl   = cslp[0];            // cache_seq_len
  const int kvlen = cl + QL_;
  const int ntiles = (kvlen + KT_ - 1) / KT_;
  const int tps  = (ntiles + NSPLIT - 1) / NSPLIT;
  const int tt0  = s * tps;
  const int tt1  = min(ntiles, tt0 + tps);

  const int lane = t & 63;
  const int w    = t >> 6;       // wave 0..7
  const int lr   = lane & 15;
  const int lg   = lane >> 4;    // 0..3
  const int m0   = w * 16;       // this wave's first row in [0,128)

  // ---- Q A-fragments straight from global (no LDS round trip), scale*log2e folded
  const float qscale = 0.088388347648318447f * 1.4426950408889634f;
  bf16x8 aQ[4];
  {
    const int row = m0 + lr;                       // A-frag row = lane&15
    const float* src = qg + (((size_t)b*QL_ + (row & 31))*H_ + h*REP_ + (row >> 5))*D_;
    #pragma unroll
    for (int kk = 0; kk < 4; ++kk) {
      const float* p = src + kk*32 + lg*8;         // A-frag k = lg*8 + e (+32*kk)
      f32x4 v0 = *(const f32x4*)(p);
      f32x4 v1 = *(const f32x4*)(p + 4);
      ushort8 u;
      u[0]=f2bf(v0[0]*qscale); u[1]=f2bf(v0[1]*qscale); u[2]=f2bf(v0[2]*qscale); u[3]=f2bf(v0[3]*qscale);
      u[4]=f2bf(v1[0]*qscale); u[5]=f2bf(v1[1]*qscale); u[6]=f2bf(v1[2]*qscale); u[7]=f2bf(v1[3]*qscale);
      aQ[kk] = __builtin_bit_cast(bf16x8, u);
    }
  }

  f32x4 oacc[8];
  #pragma unroll
  for (int nd = 0; nd < 8; ++nd) oacc[nd] = (f32x4){0.f, 0.f, 0.f, 0.f};
  float m_run[4] = {-INFINITY, -INFINITY, -INFINITY, -INFINITY};
  float l_run[4] = {0.f, 0.f, 0.f, 0.f};
  const int base_q = (m0 + lg*4) & 31;   // C-layout row -> query index base

  // staging thread->element maps
  const int k_kl = t >> 3;           // key row 0..63
  const int k_d0 = (t & 7) * 16;     // d 0..112 step 16
  const int v_key = t & 63;
  const int v_d0  = (t >> 6) * 16;

  ushort_t* PsW = Ps + w * 16 * PS_LD;

  for (int tt = tt0; tt < tt1; ++tt) {
    const int p0 = tt * KT_;
    if (tt > tt0) __syncthreads();   // all waves done reading previous tile

    // ---- stage K tile: fp32 -> bf16, row-major, padded
    {
      const int p = p0 + k_kl;
      float tmp[16];
      const float* src;
      if (p < cl)         src = kcg + (((size_t)b*MAXSEQ_ + p)*HKV_ + h)*D_ + k_d0;
      else if (p < kvlen) src = kg  + (((size_t)b*QL_ + (p - cl))*HKV_ + h)*D_ + k_d0;
      else                src = nullptr;
      if (src) {
        #pragma unroll
        for (int j = 0; j < 4; ++j) {
          f32x4 v4 = *(const f32x4*)(src + 4*j);
          tmp[4*j+0]=v4[0]; tmp[4*j+1]=v4[1]; tmp[4*j+2]=v4[2]; tmp[4*j+3]=v4[3];
        }
      } else {
        #pragma unroll
        for (int j = 0; j < 16; ++j) tmp[j] = 0.f;
      }
      ushort8 u0, u1;
      #pragma unroll
      for (int j = 0; j < 8; ++j) { u0[j] = f2bf(tmp[j]); u1[j] = f2bf(tmp[8+j]); }
      *(ushort8*)&Ks[k_kl*KS_LD + k_d0]     = u0;
      *(ushort8*)&Ks[k_kl*KS_LD + k_d0 + 8] = u1;
    }
    // ---- stage V tile transposed: Vt[d][key]
    {
      const int p = p0 + v_key;
      float tmp[16];
      const float* src;
      if (p < cl)         src = vcg + (((size_t)b*MAXSEQ_ + p)*HKV_ + h)*D_ + v_d0;
      else if (p < kvlen) src = vg  + (((size_t)b*QL_ + (p - cl))*HKV_ + h)*D_ + v_d0;
      else                src = nullptr;
      if (src) {
        #pragma unroll
        for (int j = 0; j < 4; ++j) {
          f32x4 v4 = *(const f32x4*)(src + 4*j);
          tmp[4*j+0]=v4[0]; tmp[4*j+1]=v4[1]; tmp[4*j+2]=v4[2]; tmp[4*j+3]=v4[3];
        }
      } else {
        #pragma unroll
        for (int j = 0; j < 16; ++j) tmp[j] = 0.f;
      }
      #pragma unroll
      for (int j = 0; j < 16; ++j) Vt[(v_d0 + j)*VT_LD + v_key] = f2bf(tmp[j]);
    }
    __syncthreads();

    // ---- S = Q K^T (128x64 per block; this wave: 16x64)
    f32x4 sacc[4];
    #pragma unroll
    for (int ni = 0; ni < 4; ++ni) {
      sacc[ni] = (f32x4){0.f, 0.f, 0.f, 0.f};
      #pragma unroll
      for (int kk = 0; kk < 4; ++kk) {
        bf16x8 bk = __builtin_bit_cast(bf16x8,
            *(const ushort8*)&Ks[(ni*16 + lr)*KS_LD + kk*32 + lg*8]);
        sacc[ni] = __builtin_amdgcn_mfma_f32_16x16x32_bf16(aQ[kk], bk, sacc[ni], 0, 0, 0);
      }
    }

    // ---- causal mask (only last tile(s)): key p visible to query q iff p <= cl + q
    if (p0 + KT_ - 1 > cl) {
      #pragma unroll
      for (int ni = 0; ni < 4; ++ni) {
        const int p = p0 + ni*16 + lr;
        #pragma unroll
        for (int j = 0; j < 4; ++j)
          if (p > cl + base_q + j) sacc[ni][j] = -INFINITY;
      }
    }

    // ---- online softmax (log2 domain), row stats via 16-lane shfl_xor reduce
    float pb[4][4];
    #pragma unroll
    for (int j = 0; j < 4; ++j) {
      float tm = fmaxf(fmaxf(sacc[0][j], sacc[1][j]), fmaxf(sacc[2][j], sacc[3][j]));
      #pragma unroll
      for (int off = 1; off <= 8; off <<= 1) tm = fmaxf(tm, __shfl_xor(tm, off, 64));
      const float mn    = fmaxf(m_run[j], tm);
      const float mneff = (mn == -INFINITY) ? 0.f : mn;
      const float alpha = exp2f(m_run[j] - mneff);
      m_run[j] = mn;
      float rs = 0.f;
      #pragma unroll
      for (int ni = 0; ni < 4; ++ni) { float e = exp2f(sacc[ni][j] - mneff); pb[j][ni] = e; rs += e; }
      #pragma unroll
      for (int off = 1; off <= 8; off <<= 1) rs += __shfl_xor(rs, off, 64);
      l_run[j] = l_run[j] * alpha + rs;
      #pragma unroll
      for (int nd = 0; nd < 8; ++nd) oacc[nd][j] *= alpha;
    }

    // ---- P -> LDS (bf16) to re-layout C-frag -> A-frag
    #pragma unroll
    for (int j = 0; j < 4; ++j)
      #pragma unroll
      for (int ni = 0; ni < 4; ++ni)
        PsW[(lg*4 + j)*PS_LD + ni*16 + lr] = f2bf(pb[j][ni]);

    // ---- O += P V
    #pragma unroll
    for (int kb = 0; kb < 2; ++kb) {
      bf16x8 ap = __builtin_bit_cast(bf16x8,
          *(const ushort8*)&PsW[lr*PS_LD + kb*32 + lg*8]);
      #pragma unroll
      for (int nd = 0; nd < 8; ++nd) {
        bf16x8 bv = __builtin_bit_cast(bf16x8,
            *(const ushort8*)&Vt[(nd*16 + lr)*VT_LD + kb*32 + lg*8]);
        oacc[nd] = __builtin_amdgcn_mfma_f32_16x16x32_bf16(ap, bv, oacc[nd], 0, 0, 0);
      }
    }
  }

  // ---- epilogue
  #pragma unroll
  for (int j = 0; j < 4; ++j) {
    const int row = m0 + lg*4 + j;
    if constexpr (DIRECT) {
      const float inv = (l_run[j] > 0.f) ? 1.f / l_run[j] : 0.f;
      float* dst = outg + (((size_t)b*QL_ + (row & 31))*H_ + h*REP_ + (row >> 5))*D_;
      #pragma unroll
      for (int nd = 0; nd < 8; ++nd) dst[nd*16 + lr] = oacc[nd][j] * inv;
    } else {
      const int R = bh * ROWS_ + row;
      float* dst = opart + ((size_t)s*NROWS_TOT + R)*D_;
      #pragma unroll
      for (int nd = 0; nd < 8; ++nd) dst[nd*16 + lr] = oacc[nd][j];
      if (lr == 0) {
        mpart[s*NROWS_TOT + R] = m_run[j];
        lpart[s*NROWS_TOT + R] = l_run[j];
      }
    }
  }
}

// Combine NSPLIT=2 partials: O = sum_s 2^(m_s-m*) O_s / sum_s 2^(m_s-m*) l_s
__global__ void fa_combine(const float* __restrict__ opart,
                           const float* __restrict__ mpart,
                           const float* __restrict__ lpart,
                           float* __restrict__ outg)
{
  const int idx = (int)blockIdx.x * 256 + (int)threadIdx.x;
  const int R = idx >> 7;
  const int d = idx & 127;
  const float mA = mpart[R],            mB = mpart[NROWS_TOT + R];
  const float lA = lpart[R],            lB = lpart[NROWS_TOT + R];
  const float mm = fmaxf(mA, mB);
  const float wA = (mA == -INFINITY) ? 0.f : exp2f(mA - mm);
  const float wB = (mB == -INFINITY) ? 0.f : exp2f(mB - mm);
  const float L  = lA*wA + lB*wB;
  const float o  = opart[(size_t)R*D_ + d]*wA + opart[((size_t)NROWS_TOT + R)*D_ + d]*wB;
  const float res = (L > 0.f) ? o / L : 0.f;
  const int b   = R >> 10;
  const int h   = (R >> 7) & 7;
  const int row = R & 127;
  outg[(((size_t)b*QL_ + (row & 31))*H_ + h*REP_ + (row >> 5))*D_ + d] = res;
}

extern "C" void kernel_launch(void* const* d_in, const int* in_sizes, int n_in,
                              void* d_out, int out_size, void* d_ws, size_t ws_size,
                              hipStream_t stream)
{
  const float* qg  = (const float*)d_in[0];
  const float* kg  = (const float*)d_in[1];
  const float* vg  = (const float*)d_in[2];
  const float* kcg = (const float*)d_in[3];
  const float* vcg = (const float*)d_in[4];
  const int*   csl = (const int*)d_in[5];
  float* outg = (float*)d_out;

  const size_t need = (size_t)2 * NROWS_TOT * (D_ + 2) * sizeof(float); // ~17 MB
  if (ws_size >= need) {
    float* opart = (float*)d_ws;
    float* mpart = opart + (size_t)2 * NROWS_TOT * D_;
    float* lpart = mpart + 2 * NROWS_TOT;
    hipLaunchKernelGGL((fa_main<2, false>), dim3(2 * B_ * HKV_), dim3(NT_), 0, stream,
                       qg, kg, vg, kcg, vcg, csl, nullptr, opart, mpart, lpart);
    hipLaunchKernelGGL(fa_combine, dim3(NROWS_TOT * D_ / 256), dim3(256), 0, stream,
                       opart, mpart, lpart, outg);
  } else {
    hipLaunchKernelGGL((fa_main<1, true>), dim3(B_ * HKV_), dim3(NT_), 0, stream,
                       qg, kg, vg, kcg, vcg, csl, outg, nullptr, nullptr, nullptr);
  }
}

// Round 2
// 165.230 us; speedup vs baseline: 1.1416x; 1.1416x over previous
//
#include <hip/hip_runtime.h>

typedef unsigned short ushort_t;
typedef ushort_t ushort8 __attribute__((ext_vector_type(8)));
typedef __bf16 bf16x8 __attribute__((ext_vector_type(8)));
typedef float f32x4 __attribute__((ext_vector_type(4)));

#define B_      16
#define QL_     32
#define H_      32
#define HKV_    8
#define D_      128
#define MAXSEQ_ 8192
#define REP_    4
#define ROWS_   128
#define KT_     64
#define NT_     512
#define KS_LD   136   // 128 + 8 bf16 pad -> breaks stride-256B bank conflicts
#define VT_LD   72    // 64 + 8
#define PS_LD   72    // 64 + 8
#define NROWS_TOT (B_*HKV_*ROWS_)   // 16384
#define KVSTRIDE (HKV_*D_)          // floats between consecutive keys

// Flash attention main kernel. Block = (b, kv_head, split). 8 waves, each owns
// 16 of the 128 (rep*QL) query rows. 16x16x32 bf16 MFMA; scores in log2 domain.
// Pipeline: issue tile t+1 global loads at top of tile t compute (prefetch into
// regs), convert+write LDS after the post-compute barrier.
template<int NSPLIT, bool DIRECT>
__global__ __launch_bounds__(NT_, 2)
void fa_main(const float* __restrict__ qg, const float* __restrict__ kg,
             const float* __restrict__ vg, const float* __restrict__ kcg,
             const float* __restrict__ vcg, const int* __restrict__ cslp,
             float* __restrict__ outg, float* __restrict__ opart,
             float* __restrict__ mpart, float* __restrict__ lpart)
{
  __shared__ __align__(16) ushort_t Ks[KT_ * KS_LD];     // K tile [key][d]
  __shared__ __align__(16) ushort_t Vt[D_ * VT_LD];      // V tile transposed [d][key]
  __shared__ __align__(16) ushort_t Ps[8 * 16 * PS_LD];  // per-wave P [row][key]

  const int t    = threadIdx.x;
  const int s    = (int)blockIdx.x % NSPLIT;
  const int bh   = (int)blockIdx.x / NSPLIT;
  const int b    = bh / HKV_;
  const int h    = bh % HKV_;
  const int cl   = cslp[0];            // cache_seq_len
  const int kvlen = cl + QL_;
  const int ntiles = (kvlen + KT_ - 1) / KT_;
  const int tps  = (ntiles + NSPLIT - 1) / NSPLIT;
  const int tt0  = s * tps;
  const int tt1  = min(ntiles, tt0 + tps);

  const int lane = t & 63;
  const int w    = t >> 6;       // wave 0..7
  const int lr   = lane & 15;
  const int lg   = lane >> 4;    // 0..3
  const int m0   = w * 16;       // this wave's first row in [0,128)

  // ---- Q A-fragments straight from global, scale*log2e folded
  const float qscale = 0.088388347648318447f * 1.4426950408889634f;
  bf16x8 aQ[4];
  {
    const int row = m0 + lr;                       // A-frag row = lane&15
    const float* src = qg + (((size_t)b*QL_ + (row & 31))*H_ + h*REP_ + (row >> 5))*D_;
    #pragma unroll
    for (int kk = 0; kk < 4; ++kk) {
      const float* p = src + kk*32 + lg*8;         // A-frag k = lg*8 + e
      f32x4 v0 = *(const f32x4*)(p);
      f32x4 v1 = *(const f32x4*)(p + 4);
      bf16x8 u;
      u[0]=(__bf16)(v0[0]*qscale); u[1]=(__bf16)(v0[1]*qscale);
      u[2]=(__bf16)(v0[2]*qscale); u[3]=(__bf16)(v0[3]*qscale);
      u[4]=(__bf16)(v1[0]*qscale); u[5]=(__bf16)(v1[1]*qscale);
      u[6]=(__bf16)(v1[2]*qscale); u[7]=(__bf16)(v1[3]*qscale);
      aQ[kk] = u;
    }
  }

  f32x4 oacc[8];
  #pragma unroll
  for (int nd = 0; nd < 8; ++nd) oacc[nd] = (f32x4){0.f, 0.f, 0.f, 0.f};
  float m_run[4] = {-INFINITY, -INFINITY, -INFINITY, -INFINITY};
  float l_run[4] = {0.f, 0.f, 0.f, 0.f};
  const int base_q = (m0 + lg*4) & 31;

  // staging thread->element maps
  const int k_kl = t >> 3;           // key row 0..63
  const int k_d0 = (t & 7) * 16;     // d 0..112 step 16
  const int v_key = t & 63;
  const int v_d0  = (t >> 6) * 16;

  const float* kc_base = kcg + ((size_t)b*MAXSEQ_*HKV_ + h)*D_ + k_d0;
  const float* kn_base = kg  + ((size_t)b*QL_*HKV_ + h)*D_ + k_d0;
  const float* vc_base = vcg + ((size_t)b*MAXSEQ_*HKV_ + h)*D_ + v_d0;
  const float* vn_base = vg  + ((size_t)b*QL_*HKV_ + h)*D_ + v_d0;

  ushort_t* PsW = Ps + w * 16 * PS_LD;

  f32x4 kr[4], vr[4];   // prefetch registers (held across compute phase)

  auto issue = [&](int tt) {
    const int p0 = tt * KT_;
    {
      int p = p0 + k_kl; if (p > kvlen - 1) p = kvlen - 1;
      const float* src = (p < cl) ? kc_base + (size_t)p*KVSTRIDE
                                  : kn_base + (size_t)(p - cl)*KVSTRIDE;
      #pragma unroll
      for (int j2 = 0; j2 < 4; ++j2) kr[j2] = *(const f32x4*)(src + 4*j2);
    }
    {
      int p = p0 + v_key; if (p > kvlen - 1) p = kvlen - 1;
      const float* src = (p < cl) ? vc_base + (size_t)p*KVSTRIDE
                                  : vn_base + (size_t)(p - cl)*KVSTRIDE;
      #pragma unroll
      for (int j2 = 0; j2 < 4; ++j2) vr[j2] = *(const f32x4*)(src + 4*j2);
    }
  };

  auto commit = [&]() {
    ushort8 u0, u1;
    #pragma unroll
    for (int j2 = 0; j2 < 2; ++j2) {
      #pragma unroll
      for (int e = 0; e < 4; ++e) {
        u0[j2*4+e] = __builtin_bit_cast(ushort_t, (__bf16)kr[j2][e]);
        u1[j2*4+e] = __builtin_bit_cast(ushort_t, (__bf16)kr[2+j2][e]);
      }
    }
    *(ushort8*)&Ks[k_kl*KS_LD + k_d0]     = u0;
    *(ushort8*)&Ks[k_kl*KS_LD + k_d0 + 8] = u1;
    #pragma unroll
    for (int j2 = 0; j2 < 4; ++j2)
      #pragma unroll
      for (int e = 0; e < 4; ++e)
        Vt[(v_d0 + j2*4 + e)*VT_LD + v_key] =
            __builtin_bit_cast(ushort_t, (__bf16)vr[j2][e]);
  };

  if (tt0 < tt1) { issue(tt0); commit(); }
  __syncthreads();

  for (int tt = tt0; tt < tt1; ++tt) {
    const bool hasNext = (tt + 1 < tt1);
    if (hasNext) issue(tt + 1);          // loads fly during compute

    const int p0 = tt * KT_;

    // ---- S = Q K^T (this wave: 16x64)
    f32x4 sacc[4];
    #pragma unroll
    for (int ni = 0; ni < 4; ++ni) {
      sacc[ni] = (f32x4){0.f, 0.f, 0.f, 0.f};
      #pragma unroll
      for (int kk = 0; kk < 4; ++kk) {
        bf16x8 bk = __builtin_bit_cast(bf16x8,
            *(const ushort8*)&Ks[(ni*16 + lr)*KS_LD + kk*32 + lg*8]);
        sacc[ni] = __builtin_amdgcn_mfma_f32_16x16x32_bf16(aQ[kk], bk, sacc[ni], 0, 0, 0);
      }
    }

    // ---- causal mask: key p visible to query q iff p <= cl + q
    if (p0 + KT_ - 1 > cl) {
      #pragma unroll
      for (int ni = 0; ni < 4; ++ni) {
        const int p = p0 + ni*16 + lr;
        #pragma unroll
        for (int j = 0; j < 4; ++j)
          if (p > cl + base_q + j) sacc[ni][j] = -INFINITY;
      }
    }

    // ---- online softmax (log2 domain) with defer-max (T13, exact)
    float pb[4][4];
    #pragma unroll
    for (int j = 0; j < 4; ++j) {
      float tm = fmaxf(fmaxf(sacc[0][j], sacc[1][j]), fmaxf(sacc[2][j], sacc[3][j]));
      #pragma unroll
      for (int off = 1; off <= 8; off <<= 1) tm = fmaxf(tm, __shfl_xor(tm, off, 64));
      if (__any(tm > m_run[j] + 11.5f)) {          // 8*log2e in log2 domain
        const float mn    = fmaxf(m_run[j], tm);
        const float mneff2 = (mn == -INFINITY) ? 0.f : mn;
        const float alpha = exp2f(m_run[j] - mneff2);
        m_run[j] = mn;
        l_run[j] *= alpha;
        #pragma unroll
        for (int nd = 0; nd < 8; ++nd) oacc[nd][j] *= alpha;
      }
      const float mneff = (m_run[j] == -INFINITY) ? 0.f : m_run[j];
      float rs = 0.f;
      #pragma unroll
      for (int ni = 0; ni < 4; ++ni) { float e = exp2f(sacc[ni][j] - mneff); pb[j][ni] = e; rs += e; }
      #pragma unroll
      for (int off = 1; off <= 8; off <<= 1) rs += __shfl_xor(rs, off, 64);
      l_run[j] += rs;
    }

    // ---- P -> LDS (bf16) to re-layout C-frag -> A-frag
    #pragma unroll
    for (int j = 0; j < 4; ++j)
      #pragma unroll
      for (int ni = 0; ni < 4; ++ni)
        PsW[(lg*4 + j)*PS_LD + ni*16 + lr] =
            __builtin_bit_cast(ushort_t, (__bf16)pb[j][ni]);

    // ---- O += P V
    #pragma unroll
    for (int kb = 0; kb < 2; ++kb) {
      bf16x8 ap = __builtin_bit_cast(bf16x8,
          *(const ushort8*)&PsW[lr*PS_LD + kb*32 + lg*8]);
      #pragma unroll
      for (int nd = 0; nd < 8; ++nd) {
        bf16x8 bv = __builtin_bit_cast(bf16x8,
            *(const ushort8*)&Vt[(nd*16 + lr)*VT_LD + kb*32 + lg*8]);
        oacc[nd] = __builtin_amdgcn_mfma_f32_16x16x32_bf16(ap, bv, oacc[nd], 0, 0, 0);
      }
    }

    __syncthreads();            // readers done (also drains prefetch vmcnt)
    if (hasNext) commit();      // convert + LDS write for tile tt+1
    __syncthreads();            // writes visible
  }

  // ---- epilogue
  #pragma unroll
  for (int j = 0; j < 4; ++j) {
    const int row = m0 + lg*4 + j;
    if constexpr (DIRECT) {
      const float inv = (l_run[j] > 0.f) ? 1.f / l_run[j] : 0.f;
      float* dst = outg + (((size_t)b*QL_ + (row & 31))*H_ + h*REP_ + (row >> 5))*D_;
      #pragma unroll
      for (int nd = 0; nd < 8; ++nd) dst[nd*16 + lr] = oacc[nd][j] * inv;
    } else {
      const int R = bh * ROWS_ + row;
      float* dst = opart + ((size_t)s*NROWS_TOT + R)*D_;
      #pragma unroll
      for (int nd = 0; nd < 8; ++nd) dst[nd*16 + lr] = oacc[nd][j];
      if (lr == 0) {
        mpart[s*NROWS_TOT + R] = m_run[j];
        lpart[s*NROWS_TOT + R] = l_run[j];
      }
    }
  }
}

// Combine NS partials: O = sum_s 2^(m_s-m*) O_s / sum_s 2^(m_s-m*) l_s
template<int NS>
__global__ void fa_combine(const float* __restrict__ opart,
                           const float* __restrict__ mpart,
                           const float* __restrict__ lpart,
                           float* __restrict__ outg)
{
  const int idx = (int)blockIdx.x * 256 + (int)threadIdx.x;
  const int R = idx >> 7;
  const int d = idx & 127;
  float mm = -INFINITY;
  #pragma unroll
  for (int si = 0; si < NS; ++si) mm = fmaxf(mm, mpart[si*NROWS_TOT + R]);
  float L = 0.f, o = 0.f;
  #pragma unroll
  for (int si = 0; si < NS; ++si) {
    const float ms = mpart[si*NROWS_TOT + R];
    const float wgt = (ms == -INFINITY) ? 0.f : exp2f(ms - mm);
    L += lpart[si*NROWS_TOT + R] * wgt;
    o += opart[((size_t)si*NROWS_TOT + R)*D_ + d] * wgt;
  }
  const float res = (L > 0.f) ? o / L : 0.f;
  const int b   = R >> 10;
  const int h   = (R >> 7) & 7;
  const int row = R & 127;
  outg[(((size_t)b*QL_ + (row & 31))*H_ + h*REP_ + (row >> 5))*D_ + d] = res;
}

extern "C" void kernel_launch(void* const* d_in, const int* in_sizes, int n_in,
                              void* d_out, int out_size, void* d_ws, size_t ws_size,
                              hipStream_t stream)
{
  const float* qg  = (const float*)d_in[0];
  const float* kg  = (const float*)d_in[1];
  const float* vg  = (const float*)d_in[2];
  const float* kcg = (const float*)d_in[3];
  const float* vcg = (const float*)d_in[4];
  const int*   csl = (const int*)d_in[5];
  float* outg = (float*)d_out;

  const size_t need4 = (size_t)4 * NROWS_TOT * (D_ + 2) * sizeof(float); // ~34 MB
  const size_t need2 = (size_t)2 * NROWS_TOT * (D_ + 2) * sizeof(float); // ~17 MB
  if (ws_size >= need4) {
    float* opart = (float*)d_ws;
    float* mpart = opart + (size_t)4 * NROWS_TOT * D_;
    float* lpart = mpart + 4 * NROWS_TOT;
    hipLaunchKernelGGL((fa_main<4, false>), dim3(4 * B_ * HKV_), dim3(NT_), 0, stream,
                       qg, kg, vg, kcg, vcg, csl, nullptr, opart, mpart, lpart);
    hipLaunchKernelGGL((fa_combine<4>), dim3(NROWS_TOT * D_ / 256), dim3(256), 0, stream,
                       opart, mpart, lpart, outg);
  } else if (ws_size >= need2) {
    float* opart = (float*)d_ws;
    float* mpart = opart + (size_t)2 * NROWS_TOT * D_;
    float* lpart = mpart + 2 * NROWS_TOT;
    hipLaunchKernelGGL((fa_main<2, false>), dim3(2 * B_ * HKV_), dim3(NT_), 0, stream,
                       qg, kg, vg, kcg, vcg, csl, nullptr, opart, mpart, lpart);
    hipLaunchKernelGGL((fa_combine<2>), dim3(NROWS_TOT * D_ / 256), dim3(256), 0, stream,
                       opart, mpart, lpart, outg);
  } else {
    hipLaunchKernelGGL((fa_main<1, true>), dim3(B_ * HKV_), dim3(NT_), 0, stream,
                       qg, kg, vg, kcg, vcg, csl, outg, nullptr, nullptr, nullptr);
  }
}

// Round 3
// 162.045 us; speedup vs baseline: 1.1640x; 1.0197x over previous
//
#include <hip/hip_runtime.h>

typedef unsigned short ushort_t;
typedef ushort_t ushort8 __attribute__((ext_vector_type(8)));
typedef __bf16 bf16x8 __attribute__((ext_vector_type(8)));
typedef float f32x4 __attribute__((ext_vector_type(4)));

#define B_      16
#define QL_     32
#define H_      32
#define HKV_    8
#define D_      128
#define MAXSEQ_ 8192
#define REP_    4
#define ROWS_   128
#define KT_     64
#define NT_     512
#define KS_LD   136   // 128 + 8 bf16 pad -> breaks stride-256B bank conflicts
#define VT_LD   72    // 64 + 8
#define PS_LD   72    // 64 + 8
#define NROWS_TOT (B_*HKV_*ROWS_)   // 16384
#define KVSTRIDE (HKV_*D_)          // floats between consecutive keys

// Flash attention main kernel. Block = (b, kv_head, split). 8 waves, each owns
// 16 of the 128 (rep*QL) query rows. 16x16x32 bf16 MFMA; scores in log2 domain.
// Pipeline: issue tile t+1 global loads at top of tile t compute (prefetch into
// regs), convert+write LDS after the post-compute barrier.
// __launch_bounds__(512,4): cap VGPR at 128 so TWO blocks fit per CU (LDS is
// 54 KB/block) -- cross-block overlap hides barrier drains and staging VALU.
template<int NSPLIT, bool DIRECT>
__global__ __launch_bounds__(NT_, 4)
void fa_main(const float* __restrict__ qg, const float* __restrict__ kg,
             const float* __restrict__ vg, const float* __restrict__ kcg,
             const float* __restrict__ vcg, const int* __restrict__ cslp,
             float* __restrict__ outg, float* __restrict__ opart,
             float* __restrict__ mpart, float* __restrict__ lpart)
{
  __shared__ __align__(16) ushort_t Ks[KT_ * KS_LD];     // K tile [key][d]
  __shared__ __align__(16) ushort_t Vt[D_ * VT_LD];      // V tile transposed [d][key]
  __shared__ __align__(16) ushort_t Ps[8 * 16 * PS_LD];  // per-wave P [row][key]

  const int t    = threadIdx.x;
  const int s    = (int)blockIdx.x % NSPLIT;
  const int bh   = (int)blockIdx.x / NSPLIT;
  const int b    = bh / HKV_;
  const int h    = bh % HKV_;
  const int cl   = cslp[0];            // cache_seq_len
  const int kvlen = cl + QL_;
  const int ntiles = (kvlen + KT_ - 1) / KT_;
  const int tps  = (ntiles + NSPLIT - 1) / NSPLIT;
  const int tt0  = s * tps;
  const int tt1  = min(ntiles, tt0 + tps);

  const int lane = t & 63;
  const int w    = t >> 6;       // wave 0..7
  const int lr   = lane & 15;
  const int lg   = lane >> 4;    // 0..3
  const int m0   = w * 16;       // this wave's first row in [0,128)

  // ---- Q A-fragments straight from global, scale*log2e folded
  const float qscale = 0.088388347648318447f * 1.4426950408889634f;
  bf16x8 aQ[4];
  {
    const int row = m0 + lr;                       // A-frag row = lane&15
    const float* src = qg + (((size_t)b*QL_ + (row & 31))*H_ + h*REP_ + (row >> 5))*D_;
    #pragma unroll
    for (int kk = 0; kk < 4; ++kk) {
      const float* p = src + kk*32 + lg*8;         // A-frag k = lg*8 + e
      f32x4 v0 = *(const f32x4*)(p);
      f32x4 v1 = *(const f32x4*)(p + 4);
      bf16x8 u;
      u[0]=(__bf16)(v0[0]*qscale); u[1]=(__bf16)(v0[1]*qscale);
      u[2]=(__bf16)(v0[2]*qscale); u[3]=(__bf16)(v0[3]*qscale);
      u[4]=(__bf16)(v1[0]*qscale); u[5]=(__bf16)(v1[1]*qscale);
      u[6]=(__bf16)(v1[2]*qscale); u[7]=(__bf16)(v1[3]*qscale);
      aQ[kk] = u;
    }
  }

  f32x4 oacc[8];
  #pragma unroll
  for (int nd = 0; nd < 8; ++nd) oacc[nd] = (f32x4){0.f, 0.f, 0.f, 0.f};
  float m_run[4] = {-INFINITY, -INFINITY, -INFINITY, -INFINITY};
  float l_run[4] = {0.f, 0.f, 0.f, 0.f};
  const int base_q = (m0 + lg*4) & 31;

  // staging thread->element maps
  const int k_kl = t >> 3;           // key row 0..63
  const int k_d0 = (t & 7) * 16;     // d 0..112 step 16
  const int v_key = t & 63;
  const int v_d0  = (t >> 6) * 16;

  const float* kc_base = kcg + ((size_t)b*MAXSEQ_*HKV_ + h)*D_ + k_d0;
  const float* kn_base = kg  + ((size_t)b*QL_*HKV_ + h)*D_ + k_d0;
  const float* vc_base = vcg + ((size_t)b*MAXSEQ_*HKV_ + h)*D_ + v_d0;
  const float* vn_base = vg  + ((size_t)b*QL_*HKV_ + h)*D_ + v_d0;

  ushort_t* PsW = Ps + w * 16 * PS_LD;

  f32x4 kr[4], vr[4];   // prefetch registers (held across compute phase)

  auto issue = [&](int tt) {
    const int p0 = tt * KT_;
    {
      int p = p0 + k_kl; if (p > kvlen - 1) p = kvlen - 1;
      const float* src = (p < cl) ? kc_base + (size_t)p*KVSTRIDE
                                  : kn_base + (size_t)(p - cl)*KVSTRIDE;
      #pragma unroll
      for (int j2 = 0; j2 < 4; ++j2) kr[j2] = *(const f32x4*)(src + 4*j2);
    }
    {
      int p = p0 + v_key; if (p > kvlen - 1) p = kvlen - 1;
      const float* src = (p < cl) ? vc_base + (size_t)p*KVSTRIDE
                                  : vn_base + (size_t)(p - cl)*KVSTRIDE;
      #pragma unroll
      for (int j2 = 0; j2 < 4; ++j2) vr[j2] = *(const f32x4*)(src + 4*j2);
    }
  };

  auto commit = [&]() {
    ushort8 u0, u1;
    #pragma unroll
    for (int j2 = 0; j2 < 2; ++j2) {
      #pragma unroll
      for (int e = 0; e < 4; ++e) {
        u0[j2*4+e] = __builtin_bit_cast(ushort_t, (__bf16)kr[j2][e]);
        u1[j2*4+e] = __builtin_bit_cast(ushort_t, (__bf16)kr[2+j2][e]);
      }
    }
    *(ushort8*)&Ks[k_kl*KS_LD + k_d0]     = u0;
    *(ushort8*)&Ks[k_kl*KS_LD + k_d0 + 8] = u1;
    #pragma unroll
    for (int j2 = 0; j2 < 4; ++j2)
      #pragma unroll
      for (int e = 0; e < 4; ++e)
        Vt[(v_d0 + j2*4 + e)*VT_LD + v_key] =
            __builtin_bit_cast(ushort_t, (__bf16)vr[j2][e]);
  };

  if (tt0 < tt1) { issue(tt0); commit(); }
  __syncthreads();

  for (int tt = tt0; tt < tt1; ++tt) {
    const bool hasNext = (tt + 1 < tt1);
    if (hasNext) issue(tt + 1);          // loads fly during compute

    const int p0 = tt * KT_;

    // ---- S = Q K^T (this wave: 16x64)
    f32x4 sacc[4];
    #pragma unroll
    for (int ni = 0; ni < 4; ++ni) {
      sacc[ni] = (f32x4){0.f, 0.f, 0.f, 0.f};
      #pragma unroll
      for (int kk = 0; kk < 4; ++kk) {
        bf16x8 bk = __builtin_bit_cast(bf16x8,
            *(const ushort8*)&Ks[(ni*16 + lr)*KS_LD + kk*32 + lg*8]);
        sacc[ni] = __builtin_amdgcn_mfma_f32_16x16x32_bf16(aQ[kk], bk, sacc[ni], 0, 0, 0);
      }
    }

    // ---- causal mask: key p visible to query q iff p <= cl + q
    if (p0 + KT_ - 1 > cl) {
      #pragma unroll
      for (int ni = 0; ni < 4; ++ni) {
        const int p = p0 + ni*16 + lr;
        #pragma unroll
        for (int j = 0; j < 4; ++j)
          if (p > cl + base_q + j) sacc[ni][j] = -INFINITY;
      }
    }

    // ---- online softmax (log2 domain) with defer-max (T13, exact);
    //      P written to LDS inside the loop (keeps live range small)
    #pragma unroll
    for (int j = 0; j < 4; ++j) {
      float tm = fmaxf(fmaxf(sacc[0][j], sacc[1][j]), fmaxf(sacc[2][j], sacc[3][j]));
      #pragma unroll
      for (int off = 1; off <= 8; off <<= 1) tm = fmaxf(tm, __shfl_xor(tm, off, 64));
      if (__any(tm > m_run[j] + 11.5f)) {          // 8*log2e in log2 domain
        const float mn    = fmaxf(m_run[j], tm);
        const float mneff2 = (mn == -INFINITY) ? 0.f : mn;
        const float alpha = exp2f(m_run[j] - mneff2);
        m_run[j] = mn;
        l_run[j] *= alpha;
        #pragma unroll
        for (int nd = 0; nd < 8; ++nd) oacc[nd][j] *= alpha;
      }
      const float mneff = (m_run[j] == -INFINITY) ? 0.f : m_run[j];
      float pb[4];
      float rs = 0.f;
      #pragma unroll
      for (int ni = 0; ni < 4; ++ni) { float e = exp2f(sacc[ni][j] - mneff); pb[ni] = e; rs += e; }
      #pragma unroll
      for (int off = 1; off <= 8; off <<= 1) rs += __shfl_xor(rs, off, 64);
      l_run[j] += rs;
      #pragma unroll
      for (int ni = 0; ni < 4; ++ni)
        PsW[(lg*4 + j)*PS_LD + ni*16 + lr] =
            __builtin_bit_cast(ushort_t, (__bf16)pb[ni]);
    }

    // ---- O += P V
    #pragma unroll
    for (int kb = 0; kb < 2; ++kb) {
      bf16x8 ap = __builtin_bit_cast(bf16x8,
          *(const ushort8*)&PsW[lr*PS_LD + kb*32 + lg*8]);
      #pragma unroll
      for (int nd = 0; nd < 8; ++nd) {
        bf16x8 bv = __builtin_bit_cast(bf16x8,
            *(const ushort8*)&Vt[(nd*16 + lr)*VT_LD + kb*32 + lg*8]);
        oacc[nd] = __builtin_amdgcn_mfma_f32_16x16x32_bf16(ap, bv, oacc[nd], 0, 0, 0);
      }
    }

    __syncthreads();            // readers done (also drains prefetch vmcnt)
    if (hasNext) commit();      // convert + LDS write for tile tt+1
    __syncthreads();            // writes visible
  }

  // ---- epilogue
  #pragma unroll
  for (int j = 0; j < 4; ++j) {
    const int row = m0 + lg*4 + j;
    if constexpr (DIRECT) {
      const float inv = (l_run[j] > 0.f) ? 1.f / l_run[j] : 0.f;
      float* dst = outg + (((size_t)b*QL_ + (row & 31))*H_ + h*REP_ + (row >> 5))*D_;
      #pragma unroll
      for (int nd = 0; nd < 8; ++nd) dst[nd*16 + lr] = oacc[nd][j] * inv;
    } else {
      const int R = bh * ROWS_ + row;
      float* dst = opart + ((size_t)s*NROWS_TOT + R)*D_;
      #pragma unroll
      for (int nd = 0; nd < 8; ++nd) dst[nd*16 + lr] = oacc[nd][j];
      if (lr == 0) {
        mpart[s*NROWS_TOT + R] = m_run[j];
        lpart[s*NROWS_TOT + R] = l_run[j];
      }
    }
  }
}

// Combine NS partials: O = sum_s 2^(m_s-m*) O_s / sum_s 2^(m_s-m*) l_s
template<int NS>
__global__ void fa_combine(const float* __restrict__ opart,
                           const float* __restrict__ mpart,
                           const float* __restrict__ lpart,
                           float* __restrict__ outg)
{
  const int idx = (int)blockIdx.x * 256 + (int)threadIdx.x;
  const int R = idx >> 7;
  const int d = idx & 127;
  float mm = -INFINITY;
  #pragma unroll
  for (int si = 0; si < NS; ++si) mm = fmaxf(mm, mpart[si*NROWS_TOT + R]);
  float L = 0.f, o = 0.f;
  #pragma unroll
  for (int si = 0; si < NS; ++si) {
    const float ms = mpart[si*NROWS_TOT + R];
    const float wgt = (ms == -INFINITY) ? 0.f : exp2f(ms - mm);
    L += lpart[si*NROWS_TOT + R] * wgt;
    o += opart[((size_t)si*NROWS_TOT + R)*D_ + d] * wgt;
  }
  const float res = (L > 0.f) ? o / L : 0.f;
  const int b   = R >> 10;
  const int h   = (R >> 7) & 7;
  const int row = R & 127;
  outg[(((size_t)b*QL_ + (row & 31))*H_ + h*REP_ + (row >> 5))*D_ + d] = res;
}

extern "C" void kernel_launch(void* const* d_in, const int* in_sizes, int n_in,
                              void* d_out, int out_size, void* d_ws, size_t ws_size,
                              hipStream_t stream)
{
  const float* qg  = (const float*)d_in[0];
  const float* kg  = (const float*)d_in[1];
  const float* vg  = (const float*)d_in[2];
  const float* kcg = (const float*)d_in[3];
  const float* vcg = (const float*)d_in[4];
  const int*   csl = (const int*)d_in[5];
  float* outg = (float*)d_out;

  const size_t need4 = (size_t)4 * NROWS_TOT * (D_ + 2) * sizeof(float); // ~34 MB
  const size_t need2 = (size_t)2 * NROWS_TOT * (D_ + 2) * sizeof(float); // ~17 MB
  if (ws_size >= need4) {
    float* opart = (float*)d_ws;
    float* mpart = opart + (size_t)4 * NROWS_TOT * D_;
    float* lpart = mpart + 4 * NROWS_TOT;
    hipLaunchKernelGGL((fa_main<4, false>), dim3(4 * B_ * HKV_), dim3(NT_), 0, stream,
                       qg, kg, vg, kcg, vcg, csl, nullptr, opart, mpart, lpart);
    hipLaunchKernelGGL((fa_combine<4>), dim3(NROWS_TOT * D_ / 256), dim3(256), 0, stream,
                       opart, mpart, lpart, outg);
  } else if (ws_size >= need2) {
    float* opart = (float*)d_ws;
    float* mpart = opart + (size_t)2 * NROWS_TOT * D_;
    float* lpart = mpart + 2 * NROWS_TOT;
    hipLaunchKernelGGL((fa_main<2, false>), dim3(2 * B_ * HKV_), dim3(NT_), 0, stream,
                       qg, kg, vg, kcg, vcg, csl, nullptr, opart, mpart, lpart);
    hipLaunchKernelGGL((fa_combine<2>), dim3(NROWS_TOT * D_ / 256), dim3(256), 0, stream,
                       opart, mpart, lpart, outg);
  } else {
    hipLaunchKernelGGL((fa_main<1, true>), dim3(B_ * HKV_), dim3(NT_), 0, stream,
                       qg, kg, vg, kcg, vcg, csl, outg, nullptr, nullptr, nullptr);
  }
}

// Round 4
// 151.201 us; speedup vs baseline: 1.2475x; 1.0717x over previous
//
#include <hip/hip_runtime.h>

typedef unsigned short ushort_t;
typedef ushort_t ushort4v __attribute__((ext_vector_type(4)));
typedef ushort_t ushort8 __attribute__((ext_vector_type(8)));
typedef __bf16 bf16x8 __attribute__((ext_vector_type(8)));
typedef float f32x4 __attribute__((ext_vector_type(4)));

#define B_      16
#define QL_     32
#define H_      32
#define HKV_    8
#define D_      128
#define MAXSEQ_ 8192
#define REP_    4
#define ROWS_   128
#define KT_     64
#define NT_     512
#define KS_LD   136   // 128 + 8 bf16 pad -> breaks stride-256B bank conflicts
#define VT_LD   72    // 64 + 8
#define PS_LD   72    // 64 + 8
#define NROWS_TOT (B_*HKV_*ROWS_)   // 16384
#define KVSTRIDE (HKV_*D_)          // floats between consecutive keys

// Flash attention main kernel. Block = (b, kv_head, split). 8 waves, each owns
// 16 of the 128 (rep*QL) query rows. 16x16x32 bf16 MFMA; scores in log2 domain.
// SWAPPED QK^T: sacc = mfma(K-frag, Q-frag) -> C[key][q]; each lane holds one
// q-column's 16 key-scores in registers, so softmax max/sum are in-register
// + 2 shfl_xor (vs 32 shfls in the row-spread layout).
template<int NSPLIT, bool DIRECT>
__global__ __launch_bounds__(NT_, 4)
void fa_main(const float* __restrict__ qg, const float* __restrict__ kg,
             const float* __restrict__ vg, const float* __restrict__ kcg,
             const float* __restrict__ vcg, const int* __restrict__ cslp,
             float* __restrict__ outg, float* __restrict__ opart,
             float* __restrict__ mpart, float* __restrict__ lpart)
{
  __shared__ __align__(16) ushort_t Ks[KT_ * KS_LD];     // K tile [key][d]
  __shared__ __align__(16) ushort_t Vt[D_ * VT_LD];      // V tile transposed [d][key]
  __shared__ __align__(16) ushort_t Ps[8 * 16 * PS_LD];  // per-wave P [q][key]

  const int t    = threadIdx.x;
  const int s    = (int)blockIdx.x % NSPLIT;
  const int bh   = (int)blockIdx.x / NSPLIT;
  const int b    = bh / HKV_;
  const int h    = bh % HKV_;
  const int cl   = cslp[0];            // cache_seq_len
  const int kvlen = cl + QL_;
  const int ntiles = (kvlen + KT_ - 1) / KT_;
  const int tps  = (ntiles + NSPLIT - 1) / NSPLIT;
  const int tt0  = s * tps;
  const int tt1  = min(ntiles, tt0 + tps);

  const int lane = t & 63;
  const int w    = t >> 6;       // wave 0..7
  const int lr   = lane & 15;
  const int lg   = lane >> 4;    // 0..3
  const int m0   = w * 16;       // this wave's first row in [0,128)

  // ---- Q B-fragments straight from global, scale*log2e folded
  const float qscale = 0.088388347648318447f * 1.4426950408889634f;
  bf16x8 aQ[4];
  {
    const int row = m0 + lr;                       // frag q = lane&15
    const float* src = qg + (((size_t)b*QL_ + (row & 31))*H_ + h*REP_ + (row >> 5))*D_;
    #pragma unroll
    for (int kk = 0; kk < 4; ++kk) {
      const float* p = src + kk*32 + lg*8;         // frag k = lg*8 + e
      f32x4 v0 = *(const f32x4*)(p);
      f32x4 v1 = *(const f32x4*)(p + 4);
      bf16x8 u;
      u[0]=(__bf16)(v0[0]*qscale); u[1]=(__bf16)(v0[1]*qscale);
      u[2]=(__bf16)(v0[2]*qscale); u[3]=(__bf16)(v0[3]*qscale);
      u[4]=(__bf16)(v1[0]*qscale); u[5]=(__bf16)(v1[1]*qscale);
      u[6]=(__bf16)(v1[2]*qscale); u[7]=(__bf16)(v1[3]*qscale);
      aQ[kk] = u;
    }
  }

  f32x4 oacc[8];
  #pragma unroll
  for (int nd = 0; nd < 8; ++nd) oacc[nd] = (f32x4){0.f, 0.f, 0.f, 0.f};
  float m_run = -INFINITY;   // running max for q = m0+lr (same across lg)
  float l_run = 0.f;         // running sum for q = m0+lr
  const int q_mine = (m0 + lr) & 31;   // query index for this lane's column

  // staging thread->element maps
  const int k_kl = t >> 3;           // key row 0..63
  const int k_d0 = (t & 7) * 16;     // d 0..112 step 16
  const int v_key = t & 63;
  const int v_d0  = (t >> 6) * 16;

  const float* kc_base = kcg + ((size_t)b*MAXSEQ_*HKV_ + h)*D_ + k_d0;
  const float* kn_base = kg  + ((size_t)b*QL_*HKV_ + h)*D_ + k_d0;
  const float* vc_base = vcg + ((size_t)b*MAXSEQ_*HKV_ + h)*D_ + v_d0;
  const float* vn_base = vg  + ((size_t)b*QL_*HKV_ + h)*D_ + v_d0;

  ushort_t* PsW = Ps + w * 16 * PS_LD;

  f32x4 kr[4], vr[4];   // prefetch registers (held across compute phase)

  auto issue = [&](int tt) {
    const int p0 = tt * KT_;
    {
      int p = p0 + k_kl; if (p > kvlen - 1) p = kvlen - 1;
      const float* src = (p < cl) ? kc_base + (size_t)p*KVSTRIDE
                                  : kn_base + (size_t)(p - cl)*KVSTRIDE;
      #pragma unroll
      for (int j2 = 0; j2 < 4; ++j2) kr[j2] = *(const f32x4*)(src + 4*j2);
    }
    {
      int p = p0 + v_key; if (p > kvlen - 1) p = kvlen - 1;
      const float* src = (p < cl) ? vc_base + (size_t)p*KVSTRIDE
                                  : vn_base + (size_t)(p - cl)*KVSTRIDE;
      #pragma unroll
      for (int j2 = 0; j2 < 4; ++j2) vr[j2] = *(const f32x4*)(src + 4*j2);
    }
  };

  auto commit = [&]() {
    ushort8 u0, u1;
    #pragma unroll
    for (int j2 = 0; j2 < 2; ++j2) {
      #pragma unroll
      for (int e = 0; e < 4; ++e) {
        u0[j2*4+e] = __builtin_bit_cast(ushort_t, (__bf16)kr[j2][e]);
        u1[j2*4+e] = __builtin_bit_cast(ushort_t, (__bf16)kr[2+j2][e]);
      }
    }
    *(ushort8*)&Ks[k_kl*KS_LD + k_d0]     = u0;
    *(ushort8*)&Ks[k_kl*KS_LD + k_d0 + 8] = u1;
    #pragma unroll
    for (int j2 = 0; j2 < 4; ++j2)
      #pragma unroll
      for (int e = 0; e < 4; ++e)
        Vt[(v_d0 + j2*4 + e)*VT_LD + v_key] =
            __builtin_bit_cast(ushort_t, (__bf16)vr[j2][e]);
  };

  if (tt0 < tt1) { issue(tt0); commit(); }
  __syncthreads();

  for (int tt = tt0; tt < tt1; ++tt) {
    const bool hasNext = (tt + 1 < tt1);
    if (hasNext) issue(tt + 1);          // loads fly during compute

    const int p0 = tt * KT_;

    // ---- S^T = K Q^T (this wave: 64 keys x 16 q); C[key=ni*16+lg*4+j][q=lr]
    f32x4 sacc[4];
    #pragma unroll
    for (int ni = 0; ni < 4; ++ni) {
      sacc[ni] = (f32x4){0.f, 0.f, 0.f, 0.f};
      #pragma unroll
      for (int kk = 0; kk < 4; ++kk) {
        bf16x8 ak = __builtin_bit_cast(bf16x8,
            *(const ushort8*)&Ks[(ni*16 + lr)*KS_LD + kk*32 + lg*8]);
        sacc[ni] = __builtin_amdgcn_mfma_f32_16x16x32_bf16(ak, aQ[kk], sacc[ni], 0, 0, 0);
      }
    }

    // ---- causal mask: key p visible to query q iff p <= cl + q
    if (p0 + KT_ - 1 > cl) {
      #pragma unroll
      for (int ni = 0; ni < 4; ++ni) {
        #pragma unroll
        for (int j = 0; j < 4; ++j)
          if (p0 + ni*16 + lg*4 + j > cl + q_mine) sacc[ni][j] = -INFINITY;
      }
    }

    // ---- online softmax (log2 domain), per-lane in-register + 2 shfl steps
    float tm = sacc[0][0];
    #pragma unroll
    for (int ni = 0; ni < 4; ++ni)
      #pragma unroll
      for (int j = 0; j < 4; ++j) tm = fmaxf(tm, sacc[ni][j]);
    tm = fmaxf(tm, __shfl_xor(tm, 16, 64));
    tm = fmaxf(tm, __shfl_xor(tm, 32, 64));

    if (__any(tm > m_run + 11.5f)) {     // defer-max (T13), 8*log2e in log2 dom
      const float mn    = fmaxf(m_run, tm);
      const float alpha = exp2f(m_run - mn);     // m_run=-inf -> alpha=0
      m_run = mn;
      l_run *= alpha;
      #pragma unroll
      for (int j = 0; j < 4; ++j) {
        const float aj = __shfl(alpha, lg*4 + j, 64);  // alpha of row lg*4+j
        #pragma unroll
        for (int nd = 0; nd < 8; ++nd) oacc[nd][j] *= aj;
      }
    }

    float rs = 0.f;
    #pragma unroll
    for (int ni = 0; ni < 4; ++ni)
      #pragma unroll
      for (int j = 0; j < 4; ++j) {
        const float e = exp2f(sacc[ni][j] - m_run);
        sacc[ni][j] = e;
        rs += e;
      }
    rs += __shfl_xor(rs, 16, 64);
    rs += __shfl_xor(rs, 32, 64);
    l_run += rs;

    // ---- P^T rows -> LDS: Ps[q=lr][key], 4x ds_write_b64 (contiguous keys)
    #pragma unroll
    for (int ni = 0; ni < 4; ++ni) {
      ushort4v u;
      #pragma unroll
      for (int j = 0; j < 4; ++j)
        u[j] = __builtin_bit_cast(ushort_t, (__bf16)sacc[ni][j]);
      *(ushort4v*)&PsW[lr*PS_LD + ni*16 + lg*4] = u;
    }

    // ---- O += P V   (A = P[q][key] from LDS, B = V^T fragments)
    #pragma unroll
    for (int kb = 0; kb < 2; ++kb) {
      bf16x8 ap = __builtin_bit_cast(bf16x8,
          *(const ushort8*)&PsW[lr*PS_LD + kb*32 + lg*8]);
      #pragma unroll
      for (int nd = 0; nd < 8; ++nd) {
        bf16x8 bv = __builtin_bit_cast(bf16x8,
            *(const ushort8*)&Vt[(nd*16 + lr)*VT_LD + kb*32 + lg*8]);
        oacc[nd] = __builtin_amdgcn_mfma_f32_16x16x32_bf16(ap, bv, oacc[nd], 0, 0, 0);
      }
    }

    __syncthreads();            // readers done (also drains prefetch vmcnt)
    if (hasNext) commit();      // convert + LDS write for tile tt+1
    __syncthreads();            // writes visible
  }

  // ---- epilogue
  if constexpr (DIRECT) {
    float linv[4];
    #pragma unroll
    for (int j = 0; j < 4; ++j) {
      const float lj = __shfl(l_run, lg*4 + j, 64);
      linv[j] = (lj > 0.f) ? 1.f / lj : 0.f;
    }
    #pragma unroll
    for (int j = 0; j < 4; ++j) {
      const int row = m0 + lg*4 + j;
      float* dst = outg + (((size_t)b*QL_ + (row & 31))*H_ + h*REP_ + (row >> 5))*D_;
      #pragma unroll
      for (int nd = 0; nd < 8; ++nd) dst[nd*16 + lr] = oacc[nd][j] * linv[j];
    }
  } else {
    #pragma unroll
    for (int j = 0; j < 4; ++j) {
      const int row = m0 + lg*4 + j;
      const int R = bh * ROWS_ + row;
      float* dst = opart + ((size_t)s*NROWS_TOT + R)*D_;
      #pragma unroll
      for (int nd = 0; nd < 8; ++nd) dst[nd*16 + lr] = oacc[nd][j];
    }
    if (lane < 16) {             // lane lr holds stats for row m0+lr
      const int R = bh * ROWS_ + m0 + lane;
      mpart[s*NROWS_TOT + R] = m_run;
      lpart[s*NROWS_TOT + R] = l_run;
    }
  }
}

// Combine NS partials: O = sum_s 2^(m_s-m*) O_s / sum_s 2^(m_s-m*) l_s
template<int NS>
__global__ void fa_combine(const float* __restrict__ opart,
                           const float* __restrict__ mpart,
                           const float* __restrict__ lpart,
                           float* __restrict__ outg)
{
  const int idx = (int)blockIdx.x * 256 + (int)threadIdx.x;
  const int R = idx >> 7;
  const int d = idx & 127;
  float mm = -INFINITY;
  #pragma unroll
  for (int si = 0; si < NS; ++si) mm = fmaxf(mm, mpart[si*NROWS_TOT + R]);
  float L = 0.f, o = 0.f;
  #pragma unroll
  for (int si = 0; si < NS; ++si) {
    const float ms = mpart[si*NROWS_TOT + R];
    const float wgt = (ms == -INFINITY) ? 0.f : exp2f(ms - mm);
    L += lpart[si*NROWS_TOT + R] * wgt;
    o += opart[((size_t)si*NROWS_TOT + R)*D_ + d] * wgt;
  }
  const float res = (L > 0.f) ? o / L : 0.f;
  const int b   = R >> 10;
  const int h   = (R >> 7) & 7;
  const int row = R & 127;
  outg[(((size_t)b*QL_ + (row & 31))*H_ + h*REP_ + (row >> 5))*D_ + d] = res;
}

extern "C" void kernel_launch(void* const* d_in, const int* in_sizes, int n_in,
                              void* d_out, int out_size, void* d_ws, size_t ws_size,
                              hipStream_t stream)
{
  const float* qg  = (const float*)d_in[0];
  const float* kg  = (const float*)d_in[1];
  const float* vg  = (const float*)d_in[2];
  const float* kcg = (const float*)d_in[3];
  const float* vcg = (const float*)d_in[4];
  const int*   csl = (const int*)d_in[5];
  float* outg = (float*)d_out;

  const size_t need4 = (size_t)4 * NROWS_TOT * (D_ + 2) * sizeof(float); // ~34 MB
  const size_t need2 = (size_t)2 * NROWS_TOT * (D_ + 2) * sizeof(float); // ~17 MB
  if (ws_size >= need4) {
    float* opart = (float*)d_ws;
    float* mpart = opart + (size_t)4 * NROWS_TOT * D_;
    float* lpart = mpart + 4 * NROWS_TOT;
    hipLaunchKernelGGL((fa_main<4, false>), dim3(4 * B_ * HKV_), dim3(NT_), 0, stream,
                       qg, kg, vg, kcg, vcg, csl, nullptr, opart, mpart, lpart);
    hipLaunchKernelGGL((fa_combine<4>), dim3(NROWS_TOT * D_ / 256), dim3(256), 0, stream,
                       opart, mpart, lpart, outg);
  } else if (ws_size >= need2) {
    float* opart = (float*)d_ws;
    float* mpart = opart + (size_t)2 * NROWS_TOT * D_;
    float* lpart = mpart + 2 * NROWS_TOT;
    hipLaunchKernelGGL((fa_main<2, false>), dim3(2 * B_ * HKV_), dim3(NT_), 0, stream,
                       qg, kg, vg, kcg, vcg, csl, nullptr, opart, mpart, lpart);
    hipLaunchKernelGGL((fa_combine<2>), dim3(NROWS_TOT * D_ / 256), dim3(256), 0, stream,
                       opart, mpart, lpart, outg);
  } else {
    hipLaunchKernelGGL((fa_main<1, true>), dim3(B_ * HKV_), dim3(NT_), 0, stream,
                       qg, kg, vg, kcg, vcg, csl, outg, nullptr, nullptr, nullptr);
  }
}

// Round 5
// 128.997 us; speedup vs baseline: 1.4622x; 1.1721x over previous
//
#include <hip/hip_runtime.h>

typedef unsigned short ushort_t;
typedef ushort_t ushort8 __attribute__((ext_vector_type(8)));
typedef __bf16 bf16x8 __attribute__((ext_vector_type(8)));
typedef float f32x4 __attribute__((ext_vector_type(4)));
typedef float f32x16 __attribute__((ext_vector_type(16)));
typedef unsigned uint4v __attribute__((ext_vector_type(4)));

#define B_      16
#define QL_     32
#define H_      32
#define HKV_    8
#define D_      128
#define MAXSEQ_ 8192
#define REP_    4
#define ROWS_   128
#define KT_     64
#define NT_     256
#define KS_LD   136   // ushorts; 272B rows -> dword-stride 68 (=4 mod 32), uniform 4x bank spread
#define VT_LD   72    // ushorts; 144B rows (16B-mult for b128 reads)
#define NROWS_TOT (B_*HKV_*ROWS_)   // 16384
#define KVSTRIDE (HKV_*D_)          // floats between consecutive keys

__device__ __forceinline__ unsigned pkbf(float lo, float hi2) {
  unsigned a  = (unsigned)__builtin_bit_cast(ushort_t, (__bf16)lo);
  unsigned b2 = (unsigned)__builtin_bit_cast(ushort_t, (__bf16)hi2);
  return a | (b2 << 16);
}

// Flash attention, 32x32x16 MFMA structure. Block = (b, kv_head, split),
// 4 waves; wave w owns rep-head w (32 q rows x 64 keys/tile).
// Swapped QK^T: sacc = mfma(K,Q) -> C[key][q], lane holds q-column (q=lane&31).
// P-fragments rebuilt IN REGISTERS via bf16-pack + v_permlane32_swap_b32 (T12):
// no P LDS buffer at all. Softmax in-reg + 1 shfl_xor(32).
template<int NSPLIT, bool DIRECT>
__global__ __launch_bounds__(NT_, 2)
void fa_main(const float* __restrict__ qg, const float* __restrict__ kg,
             const float* __restrict__ vg, const float* __restrict__ kcg,
             const float* __restrict__ vcg, const int* __restrict__ cslp,
             float* __restrict__ outg, float* __restrict__ opart,
             float* __restrict__ mpart, float* __restrict__ lpart)
{
  __shared__ __align__(16) ushort_t Ks[KT_ * KS_LD];   // K tile [key][d] bf16
  __shared__ __align__(16) ushort_t Vt[D_ * VT_LD];    // V tile transposed [d][key] bf16

  const int t    = threadIdx.x;
  const int s    = (int)blockIdx.x % NSPLIT;
  const int bh   = (int)blockIdx.x / NSPLIT;
  const int b    = bh / HKV_;
  const int h    = bh % HKV_;
  const int cl   = cslp[0];            // cache_seq_len
  const int kvlen = cl + QL_;
  const int ntiles = (kvlen + KT_ - 1) / KT_;
  const int tps  = (ntiles + NSPLIT - 1) / NSPLIT;
  const int tt0  = s * tps;
  const int tt1  = min(ntiles, tt0 + tps);

  const int lane = t & 63;
  const int w    = t >> 6;        // wave 0..3 = rep-head index
  const int qcol = lane & 31;     // this lane's q (B-frag col / C col)
  const int hi   = lane >> 5;     // 0/1: k-half of fragments

  // ---- Q B-fragments (col=q=lane&31, k = ks*16 + hi*8 + e), scale*log2e folded
  const float qscale = 0.088388347648318447f * 1.4426950408889634f;
  bf16x8 aQ[8];
  {
    const float* src = qg + (((size_t)b*QL_ + qcol)*H_ + h*REP_ + w)*D_ + hi*8;
    #pragma unroll
    for (int ks = 0; ks < 8; ++ks) {
      f32x4 v0 = *(const f32x4*)(src + ks*16);
      f32x4 v1 = *(const f32x4*)(src + ks*16 + 4);
      bf16x8 u;
      u[0]=(__bf16)(v0[0]*qscale); u[1]=(__bf16)(v0[1]*qscale);
      u[2]=(__bf16)(v0[2]*qscale); u[3]=(__bf16)(v0[3]*qscale);
      u[4]=(__bf16)(v1[0]*qscale); u[5]=(__bf16)(v1[1]*qscale);
      u[6]=(__bf16)(v1[2]*qscale); u[7]=(__bf16)(v1[3]*qscale);
      aQ[ks] = u;
    }
  }

  f32x16 oacc[4];                  // O[q][d], d-group db: col=d=db*32+qcol
  #pragma unroll
  for (int db = 0; db < 4; ++db)
    #pragma unroll
    for (int r = 0; r < 16; ++r) oacc[db][r] = 0.f;
  float m_run = -INFINITY;         // per-lane q stats (lanes q and q+32 identical)
  float l_run = 0.f;

  // staging thread->element maps (256 threads)
  const int k_kl = t >> 2;           // K: key row 0..63
  const int k_d0 = (t & 3) * 32;     // K: 32 floats starting here
  const int v_k2 = (t & 31) * 2;     // V: 2 adjacent keys
  const int v_d0 = (t >> 5) * 16;    // V: 16 floats starting here

  const float* kc_base = kcg + (size_t)b*MAXSEQ_*KVSTRIDE + h*D_ + k_d0;
  const float* kn_base = kg  + (size_t)b*QL_*KVSTRIDE    + h*D_ + k_d0;
  const float* vc_base = vcg + (size_t)b*MAXSEQ_*KVSTRIDE + h*D_ + v_d0;
  const float* vn_base = vg  + (size_t)b*QL_*KVSTRIDE    + h*D_ + v_d0;

  f32x4 kr[8], vr[8];   // prefetch registers (held across compute phase)

  auto issue = [&](int tt) {
    const int p0 = tt * KT_;
    {
      int p = p0 + k_kl; if (p > kvlen - 1) p = kvlen - 1;
      const float* src = (p < cl) ? kc_base + (size_t)p*KVSTRIDE
                                  : kn_base + (size_t)(p - cl)*KVSTRIDE;
      #pragma unroll
      for (int j = 0; j < 8; ++j) kr[j] = *(const f32x4*)(src + 4*j);
    }
    #pragma unroll
    for (int kk = 0; kk < 2; ++kk) {
      int p = p0 + v_k2 + kk; if (p > kvlen - 1) p = kvlen - 1;
      const float* src = (p < cl) ? vc_base + (size_t)p*KVSTRIDE
                                  : vn_base + (size_t)(p - cl)*KVSTRIDE;
      #pragma unroll
      for (int j = 0; j < 4; ++j) vr[kk*4 + j] = *(const f32x4*)(src + 4*j);
    }
  };

  auto commit = [&]() {
    // K: 4x ds_write_b128
    #pragma unroll
    for (int c2 = 0; c2 < 4; ++c2) {
      ushort8 u;
      #pragma unroll
      for (int e = 0; e < 4; ++e) {
        u[e]   = __builtin_bit_cast(ushort_t, (__bf16)kr[c2*2][e]);
        u[4+e] = __builtin_bit_cast(ushort_t, (__bf16)kr[c2*2+1][e]);
      }
      *(ushort8*)&Ks[k_kl*KS_LD + k_d0 + c2*8] = u;
    }
    // V transposed: 16x ds_write_b32 (2 adjacent keys packed per dword)
    #pragma unroll
    for (int dj = 0; dj < 16; ++dj) {
      const unsigned pr = pkbf(vr[dj>>2][dj&3], vr[4 + (dj>>2)][dj&3]);
      *(unsigned*)&Vt[(v_d0 + dj)*VT_LD + v_k2] = pr;
    }
  };

  if (tt0 < tt1) { issue(tt0); commit(); }
  __syncthreads();

  for (int tt = tt0; tt < tt1; ++tt) {
    const bool hasNext = (tt + 1 < tt1);
    if (hasNext) issue(tt + 1);          // next-tile loads fly during compute

    const int p0 = tt * KT_;

    // ---- S^T = K Q^T : C[key][q], key-groups kg of 32
    f32x16 sacc[2];
    #pragma unroll
    for (int kg = 0; kg < 2; ++kg) {
      #pragma unroll
      for (int r = 0; r < 16; ++r) sacc[kg][r] = 0.f;
      #pragma unroll
      for (int ks = 0; ks < 8; ++ks) {
        bf16x8 ak = __builtin_bit_cast(bf16x8,
            *(const ushort8*)&Ks[(kg*32 + qcol)*KS_LD + ks*16 + hi*8]);
        sacc[kg] = __builtin_amdgcn_mfma_f32_32x32x16_bf16(ak, aQ[ks], sacc[kg], 0, 0, 0);
      }
    }

    // ---- causal mask: key p visible to q iff p <= cl + q
    if (p0 + KT_ - 1 > cl) {
      #pragma unroll
      for (int kg = 0; kg < 2; ++kg)
        #pragma unroll
        for (int r = 0; r < 16; ++r) {
          const int key = p0 + kg*32 + (r&3) + 8*(r>>2) + 4*hi;
          if (key > cl + qcol) sacc[kg][r] = -INFINITY;
        }
    }

    // ---- online softmax (log2 domain), in-register + 1 shfl_xor
    float tm = -INFINITY;
    #pragma unroll
    for (int kg = 0; kg < 2; ++kg)
      #pragma unroll
      for (int r = 0; r < 16; ++r) tm = fmaxf(tm, sacc[kg][r]);
    tm = fmaxf(tm, __shfl_xor(tm, 32, 64));

    if (__any(tm > m_run + 11.5f)) {     // defer-max (T13), 8*log2e
      const float mn    = fmaxf(m_run, tm);
      const float alpha = exp2f(m_run - mn);   // m_run=-inf -> 0
      m_run = mn;
      l_run *= alpha;
      #pragma unroll
      for (int r = 0; r < 16; ++r) {
        const int rq = (r&3) + 8*(r>>2) + 4*hi;      // q-row of oacc reg r
        const float ar = __shfl(alpha, rq, 64);
        #pragma unroll
        for (int db = 0; db < 4; ++db) oacc[db][r] *= ar;
      }
    }

    float rs = 0.f;
    #pragma unroll
    for (int kg = 0; kg < 2; ++kg)
      #pragma unroll
      for (int r = 0; r < 16; ++r) {
        const float e = exp2f(sacc[kg][r] - m_run);
        sacc[kg][r] = e;
        rs += e;
      }
    rs += __shfl_xor(rs, 32, 64);
    l_run += rs;

    // ---- P -> A-frags in registers (pack pairs + permlane32_swap), then PV
    #pragma unroll
    for (int kg = 0; kg < 2; ++kg) {
      #pragma unroll
      for (int hl = 0; hl < 2; ++hl) {           // 16-key half; kstep = kg*2+hl
        const int rb = hl * 8;
        unsigned a0 = pkbf(sacc[kg][rb+0], sacc[kg][rb+1]);  // -> e0,e1
        unsigned b0 = pkbf(sacc[kg][rb+4], sacc[kg][rb+5]);  // -> e4,e5
        unsigned a1 = pkbf(sacc[kg][rb+2], sacc[kg][rb+3]);  // -> e2,e3
        unsigned b1 = pkbf(sacc[kg][rb+6], sacc[kg][rb+7]);  // -> e6,e7
        asm volatile("v_permlane32_swap_b32 %0, %1" : "+v"(a0), "+v"(b0));
        asm volatile("v_permlane32_swap_b32 %0, %1" : "+v"(a1), "+v"(b1));
        uint4v wv; wv[0] = a0; wv[1] = a1; wv[2] = b0; wv[3] = b1;
        const bf16x8 ap = __builtin_bit_cast(bf16x8, wv);
        const int kbase = kg*32 + hl*16;         // key offset in Vt rows
        #pragma unroll
        for (int db = 0; db < 4; ++db) {
          bf16x8 bv = __builtin_bit_cast(bf16x8,
              *(const ushort8*)&Vt[(db*32 + qcol)*VT_LD + kbase + hi*8]);
          oacc[db] = __builtin_amdgcn_mfma_f32_32x32x16_bf16(ap, bv, oacc[db], 0, 0, 0);
        }
      }
    }

    __syncthreads();            // readers done (drains prefetch vmcnt too)
    if (hasNext) commit();      // convert + LDS write for tile tt+1
    __syncthreads();            // writes visible
  }

  // ---- epilogue
  const float inv_own = (l_run > 0.f) ? 1.f / l_run : 0.f;
  if constexpr (DIRECT) {
    #pragma unroll
    for (int r = 0; r < 16; ++r) {
      const int rq = (r&3) + 8*(r>>2) + 4*hi;
      const float inv = __shfl(inv_own, rq, 64);
      float* dst = outg + (((size_t)b*QL_ + rq)*H_ + h*REP_ + w)*D_ + qcol;
      #pragma unroll
      for (int db = 0; db < 4; ++db) dst[db*32] = oacc[db][r] * inv;
    }
  } else {
    const int R0 = bh * ROWS_ + w * 32;
    #pragma unroll
    for (int r = 0; r < 16; ++r) {
      const int rq = (r&3) + 8*(r>>2) + 4*hi;
      float* dst = opart + ((size_t)s*NROWS_TOT + R0 + rq)*D_ + qcol;
      #pragma unroll
      for (int db = 0; db < 4; ++db) dst[db*32] = oacc[db][r];
    }
    if (lane < 32) {
      mpart[s*NROWS_TOT + R0 + lane] = m_run;
      lpart[s*NROWS_TOT + R0 + lane] = l_run;
    }
  }
}

// Combine NS partials: O = sum_s 2^(m_s-m*) O_s / sum_s 2^(m_s-m*) l_s
template<int NS>
__global__ void fa_combine(const float* __restrict__ opart,
                           const float* __restrict__ mpart,
                           const float* __restrict__ lpart,
                           float* __restrict__ outg)
{
  const int idx = (int)blockIdx.x * 256 + (int)threadIdx.x;
  const int R = idx >> 7;
  const int d = idx & 127;
  float mm = -INFINITY;
  #pragma unroll
  for (int si = 0; si < NS; ++si) mm = fmaxf(mm, mpart[si*NROWS_TOT + R]);
  float L = 0.f, o = 0.f;
  #pragma unroll
  for (int si = 0; si < NS; ++si) {
    const float ms = mpart[si*NROWS_TOT + R];
    const float wgt = (ms == -INFINITY) ? 0.f : exp2f(ms - mm);
    L += lpart[si*NROWS_TOT + R] * wgt;
    o += opart[((size_t)si*NROWS_TOT + R)*D_ + d] * wgt;
  }
  const float res = (L > 0.f) ? o / L : 0.f;
  const int b   = R >> 10;
  const int h   = (R >> 7) & 7;
  const int row = R & 127;
  outg[(((size_t)b*QL_ + (row & 31))*H_ + h*REP_ + (row >> 5))*D_ + d] = res;
}

extern "C" void kernel_launch(void* const* d_in, const int* in_sizes, int n_in,
                              void* d_out, int out_size, void* d_ws, size_t ws_size,
                              hipStream_t stream)
{
  const float* qg  = (const float*)d_in[0];
  const float* kg  = (const float*)d_in[1];
  const float* vg  = (const float*)d_in[2];
  const float* kcg = (const float*)d_in[3];
  const float* vcg = (const float*)d_in[4];
  const int*   csl = (const int*)d_in[5];
  float* outg = (float*)d_out;

  const size_t need4 = (size_t)4 * NROWS_TOT * (D_ + 2) * sizeof(float); // ~34 MB
  const size_t need2 = (size_t)2 * NROWS_TOT * (D_ + 2) * sizeof(float); // ~17 MB
  if (ws_size >= need4) {
    float* opart = (float*)d_ws;
    float* mpart = opart + (size_t)4 * NROWS_TOT * D_;
    float* lpart = mpart + 4 * NROWS_TOT;
    hipLaunchKernelGGL((fa_main<4, false>), dim3(4 * B_ * HKV_), dim3(NT_), 0, stream,
                       qg, kg, vg, kcg, vcg, csl, nullptr, opart, mpart, lpart);
    hipLaunchKernelGGL((fa_combine<4>), dim3(NROWS_TOT * D_ / 256), dim3(256), 0, stream,
                       opart, mpart, lpart, outg);
  } else if (ws_size >= need2) {
    float* opart = (float*)d_ws;
    float* mpart = opart + (size_t)2 * NROWS_TOT * D_;
    float* lpart = mpart + 2 * NROWS_TOT;
    hipLaunchKernelGGL((fa_main<2, false>), dim3(2 * B_ * HKV_), dim3(NT_), 0, stream,
                       qg, kg, vg, kcg, vcg, csl, nullptr, opart, mpart, lpart);
    hipLaunchKernelGGL((fa_combine<2>), dim3(NROWS_TOT * D_ / 256), dim3(256), 0, stream,
                       opart, mpart, lpart, outg);
  } else {
    hipLaunchKernelGGL((fa_main<1, true>), dim3(B_ * HKV_), dim3(NT_), 0, stream,
                       qg, kg, vg, kcg, vcg, csl, outg, nullptr, nullptr, nullptr);
  }
}